// Round 9
// baseline (3812.057 us; speedup 1.0000x reference)
//
#include <hip/hip_runtime.h>

#define KDIM 512
#define TDIM 64
#define BLOCK 512
#define NWAVE 8
#define LOG2E 1.4426950408889634f

typedef float v2f __attribute__((ext_vector_type(2)));

// d_ws layout (float offsets), ~3.1 MB (same class as R6/R8 — proven fits):
//   [0, 256K)        b2 = bias*LOG2E
//   [256K, +512K)    exchange: (b*2+h)*1024 + parity*512, 512 floats each
//   [then]           flags: 512 ints (0xAA poison < 0, monotone t handshake)
#define WS_B2     0
#define WS_XCHG   (KDIM * KDIM)
#define WS_FLAGS  (WS_XCHG + 512 * 1024)
#define WS_FLOATS (WS_FLAGS + 512)

__device__ __forceinline__ float fast_exp2(float v) { return __builtin_amdgcn_exp2f(v); }
__device__ __forceinline__ float fast_rcp(float v)  { return __builtin_amdgcn_rcpf(v); }

// v_add_f32_dpp row_ror:N — full-rate VALU lane rotation within 16-lane rows.
template <int CTRL>
__device__ __forceinline__ float dpp_add(float v) {
    const int p = __builtin_amdgcn_update_dpp(
        0, __builtin_bit_cast(int, v), CTRL, 0xF, 0xF, true);
    return v + __builtin_bit_cast(float, p);
}

// 64-lane sum: 4 DPP hops (cheap) + 2 DS hops (xor16, xor32). All lanes get sum.
__device__ __forceinline__ float row_sum64(float v) {
    v = dpp_add<0x121>(v);   // row_ror:1
    v = dpp_add<0x122>(v);   // row_ror:2
    v = dpp_add<0x124>(v);   // row_ror:4
    v = dpp_add<0x128>(v);   // row_ror:8
    v += __shfl_xor(v, 16, 64);
    v += __shfl_xor(v, 32, 64);
    return v;
}

__device__ __forceinline__ void row_sum64_x2(float& a, float& b) {
    a = dpp_add<0x121>(a); b = dpp_add<0x121>(b);
    a = dpp_add<0x122>(a); b = dpp_add<0x122>(b);
    a = dpp_add<0x124>(a); b = dpp_add<0x124>(b);
    a = dpp_add<0x128>(a); b = dpp_add<0x128>(b);
    float ta = __shfl_xor(a, 16, 64), tb = __shfl_xor(b, 16, 64);
    a += ta; b += tb;
    ta = __shfl_xor(a, 32, 64); tb = __shfl_xor(b, 32, 64);
    a += ta; b += tb;
}

__global__ __launch_bounds__(256) void prefold_kernel(
    const float* __restrict__ bias, float* __restrict__ b2)
{
    const int i = blockIdx.x * 256 + threadIdx.x;
    const float4 b = ((const float4*)bias)[i];
    ((float4*)b2)[i] = make_float4(b.x * LOG2E, b.y * LOG2E, b.z * LOG2E, b.w * LOG2E);
}

// R9: 512 blocks x 512 threads, 2 blocks/CU (all co-resident by capacity).
// Block gid: batch b = gid&255, row-half h = gid>>8; partner gid^256 is on
// the same XCD (256%8==0 under round-robin dispatch). Per-step partial-pbe
// exchange via d_ws + monotone agent-scope flags (R6-proven protocol).
__global__ __launch_bounds__(BLOCK)
__attribute__((amdgpu_waves_per_eu(4, 4)))
void hmm_pair_kernel(
    const float* __restrict__ x,           // [B, T]
    const float* __restrict__ prior_w,     // [K]
    const float* __restrict__ emission_w,  // [K, 2]
    const float* __restrict__ coeff,       // [K, K] raw
    float* __restrict__ ws,                // b2 + exchange + flags
    float* __restrict__ out)               // [B, K]
{
    __shared__ float post[KDIM];
    __shared__ float em0s[KDIM];
    __shared__ float emds[KDIM];
    __shared__ float part[NWAVE][KDIM];    // 16 KB
    __shared__ float rtmp[NWAVE];
    __shared__ float xs[TDIM];

    const int gid  = blockIdx.x;
    const int b    = gid & 255;
    const int h    = gid >> 8;             // row half
    const int tid  = threadIdx.x;
    const int lane = tid & 63;
    const int wv   = tid >> 6;             // 0..7
    const int k0   = 4 * lane;             // k0..k0+3 and 256+k0..256+k0+3

    const float* bb = ws + WS_B2;
    int* flags   = (int*)(ws + WS_FLAGS);
    int* my_flag = flags + (b * 2 + h);
    int* pr_flag = flags + (b * 2 + (1 - h));
    float* my_slot = ws + WS_XCHG + (size_t)(b * 2 + h) * 1024;
    float* pr_slot = ws + WS_XCHG + (size_t)(b * 2 + (1 - h)) * 1024;

    if (tid < TDIM) xs[tid] = x[b * TDIM + tid];
    {
        const float w0 = emission_w[2 * tid + 0];
        const float w1 = emission_w[2 * tid + 1];
        const float e0 = 1.0f / (1.0f + fast_exp2((w1 - w0) * LOG2E));
        em0s[tid] = e0;
        emds[tid] = 1.0f - 2.0f * e0;
    }
    __syncthreads();

    // ---- t = 0: full K locally (normalizers cancel) ----
    {
        const float x0 = xs[0];
        float v = fast_exp2(prior_w[tid] * LOG2E) * fmaf(x0, emds[tid], em0s[tid]);
        const float s = row_sum64(v);
        if (lane == 0) rtmp[wv] = s;
        __syncthreads();
        const float tot = ((rtmp[0] + rtmp[1]) + (rtmp[2] + rtmp[3]))
                        + ((rtmp[4] + rtmp[5]) + (rtmp[6] + rtmp[7]));
        post[tid] = v * fast_rcp(tot);
        __syncthreads();
    }

    // ---- steps t = 1 .. T-1 ----
    for (int t = 1; t < TDIM; ++t) {
        v2f acc[4];
        #pragma unroll
        for (int q = 0; q < 4; ++q) acc[q] = (v2f){0.0f, 0.0f};

        // wave wv rows: j = h*256 + wv + 8*i', pairs (jA = +16*i, jB = jA+8)
        const float* pc = coeff + (size_t)(h * 256 + wv) * KDIM + k0;
        const float* pb = bb    + (size_t)(h * 256 + wv) * KDIM + k0;

        #pragma unroll 1
        for (int i = 0; i < 16; ++i) {
            const int jA = h * 256 + wv + 16 * i;
            const float4 cA0 = *(const float4*)pc;
            const float4 cA1 = *(const float4*)(pc + 256);
            const float4 cB0 = *(const float4*)(pc + 8 * KDIM);
            const float4 cB1 = *(const float4*)(pc + 8 * KDIM + 256);
            const float4 bA0 = *(const float4*)pb;
            const float4 bA1 = *(const float4*)(pb + 256);
            const float4 bB0 = *(const float4*)(pb + 8 * KDIM);
            const float4 bB1 = *(const float4*)(pb + 8 * KDIM + 256);
            pc += 16 * KDIM; pb += 16 * KDIM;

            const v2f cav[4] = {{cA0.x, cA0.y}, {cA0.z, cA0.w}, {cA1.x, cA1.y}, {cA1.z, cA1.w}};
            const v2f cbv[4] = {{cB0.x, cB0.y}, {cB0.z, cB0.w}, {cB1.x, cB1.y}, {cB1.z, cB1.w}};
            const v2f bav[4] = {{bA0.x, bA0.y}, {bA0.z, bA0.w}, {bA1.x, bA1.y}, {bA1.z, bA1.w}};
            const v2f bbv[4] = {{bB0.x, bB0.y}, {bB0.z, bB0.w}, {bB1.x, bB1.y}, {bB1.z, bB1.w}};

            const float pA = post[jA];
            const float pB = post[jA + 8];
            const float pAL = pA * LOG2E;
            const float pBL = pB * LOG2E;
            const v2f pAv = {pAL, pAL};
            const v2f pBv = {pBL, pBL};

            v2f eA[4], eB[4];
            #pragma unroll
            for (int q = 0; q < 4; ++q) {
                const v2f aA = __builtin_elementwise_fma(pAv, cav[q], bav[q]);
                const v2f aB = __builtin_elementwise_fma(pBv, cbv[q], bbv[q]);
                eA[q].x = fast_exp2(aA.x); eA[q].y = fast_exp2(aA.y);
                eB[q].x = fast_exp2(aB.x); eB[q].y = fast_exp2(aB.y);
            }
            const v2f tA = (eA[0] + eA[1]) + (eA[2] + eA[3]);
            const v2f tB = (eB[0] + eB[1]) + (eB[2] + eB[3]);
            float sA = tA.x + tA.y;
            float sB = tB.x + tB.y;
            row_sum64_x2(sA, sB);

            const float scA = pA * fast_rcp(sA);
            const float scB = pB * fast_rcp(sB);
            const v2f scAv = {scA, scA};
            const v2f scBv = {scB, scB};
            #pragma unroll
            for (int q = 0; q < 4; ++q) {
                acc[q] = __builtin_elementwise_fma(scAv, eA[q], acc[q]);
                acc[q] = __builtin_elementwise_fma(scBv, eB[q], acc[q]);
            }
        }

        *(float4*)(&part[wv][k0])       = make_float4(acc[0].x, acc[0].y, acc[1].x, acc[1].y);
        *(float4*)(&part[wv][256 + k0]) = make_float4(acc[2].x, acc[2].y, acc[3].x, acc[3].y);
        __syncthreads();

        // half-pbe for k = tid (8-way LDS sum, conflict-free)
        float pbe = ((part[0][tid] + part[1][tid]) + (part[2][tid] + part[3][tid]))
                  + ((part[4][tid] + part[5][tid]) + (part[6][tid] + part[7][tid]));

        // exchange with partner block
        float* slot = my_slot + (t & 1) * 512;
        __hip_atomic_store(&slot[tid], pbe, __ATOMIC_RELAXED, __HIP_MEMORY_SCOPE_AGENT);
        __syncthreads();   // vmcnt(0) drain -> all agent stores complete
        if (tid == 0) {
            __hip_atomic_store(my_flag, t, __ATOMIC_RELEASE, __HIP_MEMORY_SCOPE_AGENT);
            int f = __hip_atomic_load(pr_flag, __ATOMIC_ACQUIRE, __HIP_MEMORY_SCOPE_AGENT);
            while (f < t) {
                __builtin_amdgcn_s_sleep(1);
                f = __hip_atomic_load(pr_flag, __ATOMIC_ACQUIRE, __HIP_MEMORY_SCOPE_AGENT);
            }
        }
        __syncthreads();
        const float* pslot = pr_slot + (t & 1) * 512;
        const float other = __hip_atomic_load(&pslot[tid], __ATOMIC_RELAXED, __HIP_MEMORY_SCOPE_AGENT);

        float v = (pbe + other) * fmaf(xs[t], emds[tid], em0s[tid]);
        const float s = row_sum64(v);
        if (lane == 0) rtmp[wv] = s;
        __syncthreads();
        const float tot = ((rtmp[0] + rtmp[1]) + (rtmp[2] + rtmp[3]))
                        + ((rtmp[4] + rtmp[5]) + (rtmp[6] + rtmp[7]));
        post[tid] = v * fast_rcp(tot);
        __syncthreads();
    }

    if (h == 0) out[(size_t)b * KDIM + tid] = post[tid];
}

// ---------- fallback: single-batch kernel (no workspace needed) ----------
__global__ __launch_bounds__(1024)
__attribute__((amdgpu_waves_per_eu(4, 4)))
void hmm_forward_kernel(
    const float* __restrict__ x, const float* __restrict__ prior_w,
    const float* __restrict__ emission_w, const float* __restrict__ coeff,
    const float* __restrict__ bias, float* __restrict__ out)
{
    __shared__ float post[KDIM];
    __shared__ float em0s[KDIM];
    __shared__ float emds[KDIM];
    __shared__ float part[16][KDIM];
    __shared__ float rtmp[16];
    __shared__ float xs[TDIM];

    const int b = blockIdx.x, tid = threadIdx.x, lane = tid & 63, wv = tid >> 6;
    const int k0 = 4 * lane;

    if (tid < TDIM) xs[tid] = x[b * TDIM + tid];
    if (tid < KDIM) {
        const float w0 = emission_w[2 * tid + 0];
        const float w1 = emission_w[2 * tid + 1];
        const float e0 = 1.0f / (1.0f + fast_exp2((w1 - w0) * LOG2E));
        em0s[tid] = e0;
        emds[tid] = 1.0f - 2.0f * e0;
    }
    __syncthreads();
    {
        const float x0 = xs[0];
        float v = 0.0f;
        if (tid < KDIM)
            v = fast_exp2(prior_w[tid] * LOG2E) * fmaf(x0, emds[tid], em0s[tid]);
        float s = row_sum64(v);
        if (lane == 0) rtmp[wv] = s;
        __syncthreads();
        float tot = 0.0f;
        #pragma unroll
        for (int w2 = 0; w2 < 16; ++w2) tot += rtmp[w2];
        if (tid < KDIM) post[tid] = v * fast_rcp(tot);
        __syncthreads();
    }
    for (int t = 1; t < TDIM; ++t) {
        float acc[8];
        #pragma unroll
        for (int i = 0; i < 8; ++i) acc[i] = 0.0f;
        const float* cA = coeff + (size_t)wv * KDIM + k0;
        const float* bA = bias  + (size_t)wv * KDIM + k0;
        #pragma unroll 1
        for (int i = 0; i < 16; ++i) {
            const float4 cA0 = *(const float4*)cA;
            const float4 cA1 = *(const float4*)(cA + 256);
            const float4 cB0 = *(const float4*)(cA + 16 * KDIM);
            const float4 cB1 = *(const float4*)(cA + 16 * KDIM + 256);
            const float4 bA0 = *(const float4*)bA;
            const float4 bA1 = *(const float4*)(bA + 256);
            const float4 bB0 = *(const float4*)(bA + 16 * KDIM);
            const float4 bB1 = *(const float4*)(bA + 16 * KDIM + 256);
            cA += 32 * KDIM; bA += 32 * KDIM;
            const float pA = post[wv + 32 * i];
            const float pB = post[wv + 16 + 32 * i];
            const float eA0 = fast_exp2(fmaf(pA, cA0.x, bA0.x) * LOG2E);
            const float eA1 = fast_exp2(fmaf(pA, cA0.y, bA0.y) * LOG2E);
            const float eA2 = fast_exp2(fmaf(pA, cA0.z, bA0.z) * LOG2E);
            const float eA3 = fast_exp2(fmaf(pA, cA0.w, bA0.w) * LOG2E);
            const float eA4 = fast_exp2(fmaf(pA, cA1.x, bA1.x) * LOG2E);
            const float eA5 = fast_exp2(fmaf(pA, cA1.y, bA1.y) * LOG2E);
            const float eA6 = fast_exp2(fmaf(pA, cA1.z, bA1.z) * LOG2E);
            const float eA7 = fast_exp2(fmaf(pA, cA1.w, bA1.w) * LOG2E);
            const float eB0 = fast_exp2(fmaf(pB, cB0.x, bB0.x) * LOG2E);
            const float eB1 = fast_exp2(fmaf(pB, cB0.y, bB0.y) * LOG2E);
            const float eB2 = fast_exp2(fmaf(pB, cB0.z, bB0.z) * LOG2E);
            const float eB3 = fast_exp2(fmaf(pB, cB0.w, bB0.w) * LOG2E);
            const float eB4 = fast_exp2(fmaf(pB, cB1.x, bB1.x) * LOG2E);
            const float eB5 = fast_exp2(fmaf(pB, cB1.y, bB1.y) * LOG2E);
            const float eB6 = fast_exp2(fmaf(pB, cB1.z, bB1.z) * LOG2E);
            const float eB7 = fast_exp2(fmaf(pB, cB1.w, bB1.w) * LOG2E);
            float sA = ((eA0 + eA1) + (eA2 + eA3)) + ((eA4 + eA5) + (eA6 + eA7));
            float sB = ((eB0 + eB1) + (eB2 + eB3)) + ((eB4 + eB5) + (eB6 + eB7));
            row_sum64_x2(sA, sB);
            const float scA = pA * fast_rcp(sA);
            const float scB = pB * fast_rcp(sB);
            acc[0] = fmaf(scA, eA0, acc[0]); acc[0] = fmaf(scB, eB0, acc[0]);
            acc[1] = fmaf(scA, eA1, acc[1]); acc[1] = fmaf(scB, eB1, acc[1]);
            acc[2] = fmaf(scA, eA2, acc[2]); acc[2] = fmaf(scB, eB2, acc[2]);
            acc[3] = fmaf(scA, eA3, acc[3]); acc[3] = fmaf(scB, eB3, acc[3]);
            acc[4] = fmaf(scA, eA4, acc[4]); acc[4] = fmaf(scB, eB4, acc[4]);
            acc[5] = fmaf(scA, eA5, acc[5]); acc[5] = fmaf(scB, eB5, acc[5]);
            acc[6] = fmaf(scA, eA6, acc[6]); acc[6] = fmaf(scB, eB6, acc[6]);
            acc[7] = fmaf(scA, eA7, acc[7]); acc[7] = fmaf(scB, eB7, acc[7]);
        }
        *(float4*)(&part[wv][k0])       = make_float4(acc[0], acc[1], acc[2], acc[3]);
        *(float4*)(&part[wv][256 + k0]) = make_float4(acc[4], acc[5], acc[6], acc[7]);
        __syncthreads();
        float v = 0.0f;
        if (tid < KDIM) {
            float pbe = 0.0f;
            #pragma unroll
            for (int w2 = 0; w2 < 16; ++w2) pbe += part[w2][tid];
            v = pbe * fmaf(xs[t], emds[tid], em0s[tid]);
        }
        float s = row_sum64(v);
        if (lane == 0) rtmp[wv] = s;
        __syncthreads();
        float tot = 0.0f;
        #pragma unroll
        for (int w2 = 0; w2 < 16; ++w2) tot += rtmp[w2];
        if (tid < KDIM) post[tid] = v * fast_rcp(tot);
        __syncthreads();
    }
    if (tid < KDIM) out[b * KDIM + tid] = post[tid];
}

extern "C" void kernel_launch(void* const* d_in, const int* in_sizes, int n_in,
                              void* d_out, int out_size, void* d_ws, size_t ws_size,
                              hipStream_t stream) {
    const float* x          = (const float*)d_in[0];
    const float* prior_w    = (const float*)d_in[1];
    const float* emission_w = (const float*)d_in[2];
    const float* coeff      = (const float*)d_in[3];
    const float* bias       = (const float*)d_in[4];
    float* out              = (float*)d_out;

    if (ws_size >= (size_t)WS_FLOATS * sizeof(float)) {
        float* ws = (float*)d_ws;
        hipLaunchKernelGGL(prefold_kernel, dim3(KDIM * KDIM / 4 / 256), dim3(256),
                           0, stream, bias, ws + WS_B2);
        hipLaunchKernelGGL(hmm_pair_kernel, dim3(512), dim3(BLOCK), 0, stream,
                           x, prior_w, emission_w, coeff, ws, out);
    } else {
        hipLaunchKernelGGL(hmm_forward_kernel, dim3(256), dim3(1024), 0, stream,
                           x, prior_w, emission_w, coeff, bias, out);
    }
}